// Round 7
// baseline (578.596 us; speedup 1.0000x reference)
//
#include <hip/hip_runtime.h>

#define N_NODES 100000
#define N_EDGES 1000000
#define DIM 64
#define N_GRAPHS 1024
#define OUT_DIM 16
#define NLAYERS 4

#define BN 64        // nodes per block in layer kernel
#define NB 1563      // ceil(N_NODES/BN)
#define BLOCK 512    // 8 waves
#define NWAVES 8
#define RPW 8        // dst rows owned per wave -> no atomics
#define SA 65        // agg_s row stride: 65%32==1 -> 2-way alias, free
#define SX 68        // x_s row stride: mult of 4 for float4 LDS ops

#define SCAN_NB 98   // ceil((N_NODES+1)/1024)

__device__ __forceinline__ float b2f(unsigned short u) {
    union { unsigned int i; float f; } c;
    c.i = ((unsigned int)u) << 16;
    return c.f;
}
__device__ __forceinline__ unsigned short f2b(float f) {  // RNE
    union { float f; unsigned int i; } c;
    c.f = f;
    return (unsigned short)((c.i + 0x7FFFu + ((c.i >> 16) & 1u)) >> 16);
}

// ---------------- CSR build ----------------
__global__ void count_kernel(const int* __restrict__ dst, int* __restrict__ counts) {
    int e = blockIdx.x * blockDim.x + threadIdx.x;
    if (e < N_EDGES) atomicAdd(&counts[dst[e]], 1);  // int atomic: native
}

__global__ __launch_bounds__(1024) void scan_reduce_kernel(const int* __restrict__ counts,
                                                           int* __restrict__ bsums) {
    int i = blockIdx.x * 1024 + threadIdx.x;
    int v = (i < N_NODES) ? counts[i] : 0;
    __shared__ int ws_[16];
    for (int off = 32; off > 0; off >>= 1) v += __shfl_down(v, off, 64);
    if ((threadIdx.x & 63) == 0) ws_[threadIdx.x >> 6] = v;
    __syncthreads();
    if (threadIdx.x < 16) {
        int s = ws_[threadIdx.x];
        for (int off = 8; off > 0; off >>= 1) s += __shfl_down(s, off, 16);
        if (threadIdx.x == 0) bsums[blockIdx.x] = s;
    }
}

__global__ __launch_bounds__(128) void scan_sums_kernel(int* __restrict__ bsums) {
    __shared__ int t[128];
    int i = threadIdx.x;
    t[i] = (i < SCAN_NB) ? bsums[i] : 0;
    __syncthreads();
    for (int off = 1; off < 128; off <<= 1) {
        int v = (i >= off) ? t[i - off] : 0;
        __syncthreads();
        t[i] += v;
        __syncthreads();
    }
    if (i < SCAN_NB) bsums[i] = (i > 0) ? t[i - 1] : 0;  // exclusive
}

__global__ __launch_bounds__(1024) void scan_apply_kernel(const int* __restrict__ counts,
                                                          const int* __restrict__ bsums,
                                                          int* __restrict__ row_ptr,
                                                          int* __restrict__ cursor) {
    int i = blockIdx.x * 1024 + threadIdx.x;
    int v = (i < N_NODES) ? counts[i] : 0;
    int lane = threadIdx.x & 63, w = threadIdx.x >> 6;
    int inc = v;
    for (int off = 1; off < 64; off <<= 1) {
        int u = __shfl_up(inc, off, 64);
        if (lane >= off) inc += u;
    }
    __shared__ int wsum[16];
    if (lane == 63) wsum[w] = inc;
    __syncthreads();
    if (threadIdx.x < 16) {
        int s = wsum[threadIdx.x];
        for (int off = 1; off < 16; off <<= 1) {
            int u = __shfl_up(s, off, 16);
            if (threadIdx.x >= off) s += u;
        }
        wsum[threadIdx.x] = s;
    }
    __syncthreads();
    int excl = inc - v + (w > 0 ? wsum[w - 1] : 0) + bsums[blockIdx.x];
    if (i <= N_NODES) row_ptr[i] = excl;
    if (i < N_NODES) cursor[i] = excl;
}

__global__ void scatter_kernel(const int* __restrict__ src, const int* __restrict__ dst,
                               int* __restrict__ cursor, int* __restrict__ edges) {
    int e = blockIdx.x * blockDim.x + threadIdx.x;
    if (e < N_EDGES) {
        int pos = atomicAdd(&cursor[dst[e]], 1);  // int atomic: native
        edges[pos] = src[e];
    }
}

// ---------------- x -> bf16 convert ----------------
__global__ __launch_bounds__(256) void tobf_kernel(const float4* __restrict__ in,
                                                   ushort4* __restrict__ out) {
    const int n4 = N_NODES * (DIM / 4);
    for (int i = blockIdx.x * blockDim.x + threadIdx.x; i < n4; i += gridDim.x * blockDim.x) {
        float4 v = in[i];
        ushort4 b;
        b.x = f2b(v.x); b.y = f2b(v.y); b.z = f2b(v.z); b.w = f2b(v.w);
        out[i] = b;
    }
}

// ---------------- fused GraphConv layer ----------------
// Phase A: wave w owns dst rows [8w,8w+8). Gather from the bf16 copy of h:
//          16 lanes per src row, ushort4/lane -> 128B/row, 16-edge unroll
//          (4 loads in flight). Cross-group shfl_xor reduce, plain LDS writes.
//          Compute stays fp32 (bf16 only on the gather stream).
// Phase B: wave w computes dims [8w,8w+8) for all 64 nodes; weights wave-uniform.
// Epilogue: stores fp32 h AND its bf16 copy (next layer's gather source).
__global__ __launch_bounds__(BLOCK) void layer_kernel(
    const float* __restrict__ hin, const ushort4* __restrict__ hbf_in,
    float* __restrict__ hout, ushort4* __restrict__ hbf_out,
    const float* __restrict__ Wrel, const float* __restrict__ brel,
    const float* __restrict__ Wroot,
    const int* __restrict__ row_ptr, const int* __restrict__ edges) {
    __shared__ float agg_s[BN * SA];
    __shared__ float x_s[BN * SX];
    const int tid = threadIdx.x;
    const int lane = tid & 63;
    const int wave = __builtin_amdgcn_readfirstlane(tid >> 6);
    const int grp = lane >> 4;   // which of 4 concurrent edges
    const int gl = lane & 15;    // ushort4 slot within row (4 dims)
    const int node0 = blockIdx.x * BN;
    const int nvalid = min(BN, N_NODES - node0);

    // stage own x rows (coalesced float4)
    for (int i = tid; i < nvalid * (DIM / 4); i += BLOCK) {
        int nl = i >> 4;
        int c = i & 15;
        float4 v = reinterpret_cast<const float4*>(hin)[(size_t)(node0 + nl) * (DIM / 4) + c];
        reinterpret_cast<float4*>(x_s)[nl * (SX / 4) + c] = v;
    }

    // Phase A
    const int r0 = node0 + wave * RPW;
#pragma unroll
    for (int r8 = 0; r8 < RPW; ++r8) {
        int rg = r0 + r8;
        if (rg >= N_NODES) break;
        int e = row_ptr[rg];            // wave-uniform -> scalar
        const int ee = row_ptr[rg + 1];
        float4 acc = make_float4(0.f, 0.f, 0.f, 0.f);
        for (; e + 16 <= ee; e += 16) {   // 16 edges, 4 gather loads (2KB) in flight
            int s0 = edges[e + grp];
            int s1 = edges[e + 4 + grp];
            int s2 = edges[e + 8 + grp];
            int s3 = edges[e + 12 + grp];
            ushort4 u0 = hbf_in[(size_t)s0 * 16 + gl];
            ushort4 u1 = hbf_in[(size_t)s1 * 16 + gl];
            ushort4 u2 = hbf_in[(size_t)s2 * 16 + gl];
            ushort4 u3 = hbf_in[(size_t)s3 * 16 + gl];
            acc.x += (b2f(u0.x) + b2f(u1.x)) + (b2f(u2.x) + b2f(u3.x));
            acc.y += (b2f(u0.y) + b2f(u1.y)) + (b2f(u2.y) + b2f(u3.y));
            acc.z += (b2f(u0.z) + b2f(u1.z)) + (b2f(u2.z) + b2f(u3.z));
            acc.w += (b2f(u0.w) + b2f(u1.w)) + (b2f(u2.w) + b2f(u3.w));
        }
        for (; e + 4 <= ee; e += 4) {
            int s = edges[e + grp];
            ushort4 u = hbf_in[(size_t)s * 16 + gl];
            acc.x += b2f(u.x); acc.y += b2f(u.y); acc.z += b2f(u.z); acc.w += b2f(u.w);
        }
        int rem = ee - e;
        if (grp < rem) {
            int s = edges[e + grp];
            ushort4 u = hbf_in[(size_t)s * 16 + gl];
            acc.x += b2f(u.x); acc.y += b2f(u.y); acc.z += b2f(u.z); acc.w += b2f(u.w);
        }
        // reduce across the 4 groups (lanes differing in bits 4,5)
        acc.x += __shfl_xor(acc.x, 16, 64); acc.y += __shfl_xor(acc.y, 16, 64);
        acc.z += __shfl_xor(acc.z, 16, 64); acc.w += __shfl_xor(acc.w, 16, 64);
        acc.x += __shfl_xor(acc.x, 32, 64); acc.y += __shfl_xor(acc.y, 32, 64);
        acc.z += __shfl_xor(acc.z, 32, 64); acc.w += __shfl_xor(acc.w, 32, 64);
        if (grp == 0) {
            float* base = &agg_s[(wave * RPW + r8) * SA + gl * 4];
            base[0] = acc.x; base[1] = acc.y; base[2] = acc.z; base[3] = acc.w;
        }
    }
    __syncthreads();

    // Phase B: node = lane, dim-octet = wave
    const int d0 = wave * 8;
    float out[8];
#pragma unroll
    for (int j = 0; j < 8; ++j) out[j] = brel[d0 + j];  // uniform -> scalar
    const float* ar = &agg_s[lane * SA];
    const float* xr = &x_s[lane * SX];
    for (int k = 0; k < DIM; ++k) {
        float a = ar[k];
        float xv = xr[k];
        const float* wr = &Wrel[k * DIM + d0];   // wave-uniform -> s_load
        const float* wo = &Wroot[k * DIM + d0];
#pragma unroll
        for (int j = 0; j < 8; ++j)
            out[j] = fmaf(a, wr[j], fmaf(xv, wo[j], out[j]));
    }

    __syncthreads();  // all waves done reading x_s
    if (lane < nvalid) {
#pragma unroll
        for (int j = 0; j < 8; ++j) x_s[lane * SX + d0 + j] = fmaxf(out[j], 0.f);
    }
    __syncthreads();

    // coalesced stores: fp32 h + bf16 gather copy
    for (int i = tid; i < nvalid * (DIM / 4); i += BLOCK) {
        int nl = i >> 4;
        int c = i & 15;
        float4 v = reinterpret_cast<const float4*>(x_s)[nl * (SX / 4) + c];
        reinterpret_cast<float4*>(hout)[(size_t)(node0 + nl) * (DIM / 4) + c] = v;
        ushort4 b;
        b.x = f2b(v.x); b.y = f2b(v.y); b.z = f2b(v.z); b.w = f2b(v.w);
        hbf_out[(size_t)(node0 + nl) * 16 + c] = b;
    }
}

// ---------------- global add pool ----------------
__global__ __launch_bounds__(256) void pool_kernel(const float* __restrict__ h,
                                                   const int* __restrict__ batch,
                                                   float* __restrict__ g) {
    int gtid = blockIdx.x * blockDim.x + threadIdx.x;
    int w = gtid >> 6;
    int lane = gtid & 63;
    const int NW = 1024;
    const int CH = (N_NODES + NW - 1) / NW;  // 98
    int nb = w * CH;
    int ne = min(nb + CH, N_NODES);
    if (nb >= ne) return;
    float acc = 0.f;
    int cur = batch[nb];
    for (int n = nb; n < ne; ++n) {
        int b = batch[n];  // wave-uniform broadcast
        if (b != cur) {
            unsafeAtomicAdd(&g[(size_t)cur * DIM + lane], acc);  // native f32 atomic
            acc = 0.f;
            cur = b;
        }
        acc += h[(size_t)n * DIM + lane];
    }
    unsafeAtomicAdd(&g[(size_t)cur * DIM + lane], acc);
}

// ---------------- classifier head ----------------
__global__ __launch_bounds__(256) void head_kernel(
    const float* __restrict__ g, const float* __restrict__ W1, const float* __restrict__ b1,
    const float* __restrict__ W2, const float* __restrict__ b2, float* __restrict__ y) {
    int gid = blockIdx.x * blockDim.x + threadIdx.x;
    if (gid >= N_GRAPHS) return;
    float t[DIM];
#pragma unroll
    for (int d = 0; d < DIM; ++d) t[d] = b1[d];
    const float4* gp = reinterpret_cast<const float4*>(g + (size_t)gid * DIM);
    for (int kk = 0; kk < DIM / 4; ++kk) {
        float4 gv = gp[kk];
        float ga[4] = {gv.x, gv.y, gv.z, gv.w};
#pragma unroll
        for (int c = 0; c < 4; ++c) {
            int k = 4 * kk + c;
            float v = ga[c];
#pragma unroll
            for (int d = 0; d < DIM; ++d) t[d] = fmaf(v, W1[k * DIM + d], t[d]);
        }
    }
#pragma unroll
    for (int d = 0; d < DIM; ++d) t[d] = fmaxf(t[d], 0.f);
    for (int o = 0; o < OUT_DIM; ++o) {
        float acc = b2[o];
#pragma unroll
        for (int d = 0; d < DIM; ++d) acc = fmaf(t[d], W2[d * OUT_DIM + o], acc);
        y[(size_t)gid * OUT_DIM + o] = acc;
    }
}

extern "C" void kernel_launch(void* const* d_in, const int* in_sizes, int n_in,
                              void* d_out, int out_size, void* d_ws, size_t ws_size,
                              hipStream_t stream) {
    const float* x     = (const float*)d_in[0];
    const int*   eidx  = (const int*)d_in[1];
    const int*   batch = (const int*)d_in[2];
    const float* Wrel  = (const float*)d_in[3];
    const float* brel  = (const float*)d_in[4];
    const float* Wroot = (const float*)d_in[5];
    const float* W1    = (const float*)d_in[6];
    const float* b1    = (const float*)d_in[7];
    const float* W2    = (const float*)d_in[8];
    const float* b2    = (const float*)d_in[9];
    float* y = (float*)d_out;

    char* ws = (char*)d_ws;
    const size_t HBYTES  = (size_t)N_NODES * DIM * sizeof(float);          // 25.6 MB
    const size_t BFBYTES = (size_t)N_NODES * DIM * sizeof(unsigned short); // 12.8 MB
    size_t off = 0;
    float* hA = (float*)(ws + off); off += HBYTES;
    float* hB = (float*)(ws + off); off += HBYTES;
    ushort4* bf0 = (ushort4*)(ws + off); off += BFBYTES;
    ushort4* bf1 = (ushort4*)(ws + off); off += BFBYTES;
    int* row_ptr = (int*)(ws + off); off += (((size_t)(N_NODES + 1) * 4 + 255) / 256) * 256;
    int* cursor  = (int*)(ws + off); off += (((size_t)N_NODES * 4 + 255) / 256) * 256;
    int* edges   = (int*)(ws + off); off += (size_t)N_EDGES * 4;
    float* g     = (float*)(ws + off); off += (size_t)N_GRAPHS * DIM * 4;
    int* bsums   = (int*)(ws + off); off += 128 * 4;

    const int* src = eidx;
    const int* dst = eidx + N_EDGES;

    // CSR build (once, reused across 4 layers)
    hipMemsetAsync(row_ptr, 0, (size_t)N_NODES * sizeof(int), stream);
    count_kernel<<<(N_EDGES + 255) / 256, 256, 0, stream>>>(dst, row_ptr);
    scan_reduce_kernel<<<SCAN_NB, 1024, 0, stream>>>(row_ptr, bsums);
    scan_sums_kernel<<<1, 128, 0, stream>>>(bsums);
    scan_apply_kernel<<<SCAN_NB, 1024, 0, stream>>>(row_ptr, bsums, row_ptr, cursor);
    scatter_kernel<<<(N_EDGES + 255) / 256, 256, 0, stream>>>(src, dst, cursor, edges);

    // bf16 copy of x for the first layer's gather
    tobf_kernel<<<1024, 256, 0, stream>>>((const float4*)x, bf0);

    // 4 GraphConv layers, ping-pong (fp32 + bf16 streams)
    const float* hin = x;
    const ushort4* bin = bf0;
    float* fbufs[2] = {hA, hB};
    ushort4* bbufs[2] = {bf1, bf0};
    for (int l = 0; l < NLAYERS; ++l) {
        float* hout = fbufs[l & 1];
        ushort4* bout = bbufs[l & 1];
        layer_kernel<<<NB, BLOCK, 0, stream>>>(hin, bin, hout, bout,
                                               Wrel + (size_t)l * DIM * DIM,
                                               brel + (size_t)l * DIM,
                                               Wroot + (size_t)l * DIM * DIM,
                                               row_ptr, edges);
        hin = hout;
        bin = bout;
    }

    // global add pool
    hipMemsetAsync(g, 0, (size_t)N_GRAPHS * DIM * sizeof(float), stream);
    pool_kernel<<<256, 256, 0, stream>>>(hin, batch, g);

    // head
    head_kernel<<<(N_GRAPHS + 255) / 256, 256, 0, stream>>>(g, W1, b1, W2, b2, y);
}